// Round 11
// baseline (340.337 us; speedup 1.0000x reference)
//
#include <hip/hip_runtime.h>
#include <stdint.h>

typedef __attribute__((ext_vector_type(8))) short bf16x8;
typedef __attribute__((ext_vector_type(4))) float f32x4;

#define GM 8192
#define GN 4096
#define GK 4096
#define KT32 (GK / 32)   // 128 K-tiles of 32

__device__ __forceinline__ unsigned short f2bf(float f) {
  union { float f; unsigned int u; } c; c.f = f;
  unsigned int u = c.u;
  unsigned int r = u + 0x7FFFu + ((u >> 16) & 1u);   // round-to-nearest-even
  return (unsigned short)(r >> 16);
}

// ---------------- x (f32) -> bf16, 8 elems/thread ----------------
__global__ __launch_bounds__(256) void cvt_x_kernel(const float* __restrict__ x,
                                                    unsigned short* __restrict__ xb) {
  int i = blockIdx.x * 256 + threadIdx.x;
  const float4* p = (const float4*)x + (size_t)i * 2;
  float4 a = p[0], b = p[1];
  unsigned short t[8] = { f2bf(a.x), f2bf(a.y), f2bf(a.z), f2bf(a.w),
                          f2bf(b.x), f2bf(b.y), f2bf(b.z), f2bf(b.w) };
  int4 pk; __builtin_memcpy(&pk, t, 16);
  ((int4*)xb)[i] = pk;
}

// -------- W_eff = weight + 2 * lora_B @ lora_A -> bf16 --------
__global__ __launch_bounds__(256) void weff_kernel(const float* __restrict__ w,
                                                   const float* __restrict__ lA,
                                                   const float* __restrict__ lB,
                                                   unsigned short* __restrict__ wb) {
  const int K = GK;
  int idx = blockIdx.x * 256 + threadIdx.x;   // over (N/8)*(K/8) = 512*512
  int cg = idx & 511;
  int rg = idx >> 9;
  int i0 = cg << 3;
  int o0 = rg << 3;

  float acc[8][8];
#pragma unroll
  for (int r = 0; r < 8; ++r)
#pragma unroll
    for (int c = 0; c < 8; ++c) acc[r][c] = 0.f;

#pragma unroll
  for (int r = 0; r < 16; ++r) {
    float4 a0 = *(const float4*)(lA + (size_t)r * K + i0);
    float4 a1 = *(const float4*)(lA + (size_t)r * K + i0 + 4);
    float av[8] = { a0.x, a0.y, a0.z, a0.w, a1.x, a1.y, a1.z, a1.w };
#pragma unroll
    for (int row = 0; row < 8; ++row) {
      float b = lB[(size_t)(o0 + row) * 16 + r];
#pragma unroll
      for (int c = 0; c < 8; ++c) acc[row][c] += b * av[c];
    }
  }

#pragma unroll
  for (int row = 0; row < 8; ++row) {
    float4 w0 = *(const float4*)(w + (size_t)(o0 + row) * K + i0);
    float4 w1 = *(const float4*)(w + (size_t)(o0 + row) * K + i0 + 4);
    unsigned short t[8] = {
      f2bf(w0.x + 2.0f * acc[row][0]), f2bf(w0.y + 2.0f * acc[row][1]),
      f2bf(w0.z + 2.0f * acc[row][2]), f2bf(w0.w + 2.0f * acc[row][3]),
      f2bf(w1.x + 2.0f * acc[row][4]), f2bf(w1.y + 2.0f * acc[row][5]),
      f2bf(w1.z + 2.0f * acc[row][6]), f2bf(w1.w + 2.0f * acc[row][7]) };
    int4 pk; __builtin_memcpy(&pk, t, 16);
    *(int4*)(wb + (size_t)(o0 + row) * K + i0) = pk;
  }
}

// ========== 256x128 block / 64x64 wave bf16 GEMM, 2 blocks per CU: C = A * B^T ==========
// 8 waves (4M x 2N), 64x64 C per wave (64 AGPR acc), __launch_bounds__(512,4) -> <=128 regs
// -> 4 waves/SIMD = 2 independent 512-thread blocks resident per CU (two barrier domains:
// one block's LDS-drain/barrier stall is hidden by the other block's MFMA waves).
// LDS: 3 buffers x 24 KB (A 16 KB [16 subtiles] + B 8 KB [8 subtiles]), 16x32-bf16 subtiles,
// st_16x32 swizzle (pre-swizzled global src, 0 conflicts). Distance-2 prefetch, steady
// vmcnt(3) (3 own loads in flight, never drains). Explicit lgkmcnt(0) BEFORE each barrier:
// all my ds_reads complete before I pass the barrier, so the buffer-recycle write issued
// by other waves after that barrier (1-barrier gap, triple buffer) is WAR-safe.

__device__ __forceinline__ void gload16(const unsigned short* g, char* l) {
  __builtin_amdgcn_global_load_lds((__attribute__((address_space(1))) void*)g,
                                   (__attribute__((address_space(3))) void*)l, 16, 0, 0);
}

__device__ __forceinline__ void bar() {
  asm volatile("" ::: "memory");
  __builtin_amdgcn_s_barrier();
  asm volatile("" ::: "memory");
}

template <int N>
__device__ __forceinline__ void vmwait() {
  if constexpr (N == 0)      asm volatile("s_waitcnt vmcnt(0)" ::: "memory");
  else if constexpr (N == 3) asm volatile("s_waitcnt vmcnt(3)" ::: "memory");
}

__device__ __forceinline__ void lgkm0() {
  asm volatile("s_waitcnt lgkmcnt(0)" ::: "memory");
}

#define MFMA_BF16(a, b, c) __builtin_amdgcn_mfma_f32_16x16x32_bf16((a), (b), (c), 0, 0, 0)

// stage one BK=32 tile (A 256x32 = 16 subtiles, B 128x32 = 8 subtiles) into buffer BUF.
// wave w stages A subtiles {2w, 2w+1} and B subtile {w}: 3 gloads/wave.
template <int BUF>
__device__ __forceinline__ void stage_tile(const unsigned short* A, const unsigned short* B,
                                           char* smem, int bm0, int bn0, int w, int lane,
                                           int kt) {
  const int gcol = ((lane & 3) * 8) ^ ((lane & 32) ? 16 : 0);   // pre-swizzled source col
  const int r = lane >> 2;
  char* base = smem + BUF * 24576;
  gload16(A + (size_t)(bm0 + (2 * w) * 16 + r) * GK + kt * 32 + gcol, base + ((2 * w) << 10));
  gload16(A + (size_t)(bm0 + (2 * w + 1) * 16 + r) * GK + kt * 32 + gcol, base + ((2 * w + 1) << 10));
  gload16(B + (size_t)(bn0 + w * 16 + r) * GK + kt * 32 + gcol, base + 16384 + (w << 10));
}

__device__ __forceinline__ bf16x8 ldsA(const char* smem, int buf, int sr, int foff) {
  return *(const bf16x8*)(smem + buf * 24576 + (sr << 10) + foff);
}
__device__ __forceinline__ bf16x8 ldsB(const char* smem, int buf, int sr, int foff) {
  return *(const bf16x8*)(smem + buf * 24576 + 16384 + (sr << 10) + foff);
}

template <int BUF>
__device__ __forceinline__ void phase(const unsigned short* __restrict__ A,
                                      const unsigned short* __restrict__ B,
                                      char* smem, int bm0, int bn0, int w, int lane,
                                      int wm, int wn, int foff, int kt,
                                      f32x4 (&acc)[4][4]) {
  if (kt + 2 < KT32)
    stage_tile<(BUF + 2) % 3>(A, B, smem, bm0, bn0, w, lane, kt + 2);

  bf16x8 av[4], bv[4];
#pragma unroll
  for (int mi = 0; mi < 4; ++mi) av[mi] = ldsA(smem, BUF, wm * 4 + mi, foff);
#pragma unroll
  for (int ni = 0; ni < 4; ++ni) bv[ni] = ldsB(smem, BUF, wn * 4 + ni, foff);

  if (kt + 2 < KT32)      vmwait<3>();   // retire tile kt+1 (own 3 loads)
  else if (kt + 1 < KT32) vmwait<0>();
  lgkm0();                               // my ds_reads done -> recycle write after bar is safe
  bar();

  __builtin_amdgcn_s_setprio(1);
#pragma unroll
  for (int mi = 0; mi < 4; ++mi)
#pragma unroll
    for (int ni = 0; ni < 4; ++ni)
      acc[mi][ni] = MFMA_BF16(av[mi], bv[ni], acc[mi][ni]);
  __builtin_amdgcn_s_setprio(0);
}

__global__ __launch_bounds__(512, 4) void gemm_bt_kernel(const unsigned short* __restrict__ A,
                                                         const unsigned short* __restrict__ B,
                                                         float* __restrict__ C) {
  __shared__ alignas(16) char smem[73728];   // 3 x 24 KB

  const int t = threadIdx.x, lane = t & 63, w = t >> 6;
  const int wm = w >> 1, wn = w & 1;     // 4 x 2 wave grid, 64x64 per wave

  // bijective XCD-chunked swizzle: 1024 blocks, 1024 % 8 == 0
  const int bid = blockIdx.x;
  const int wg  = (bid & 7) * (1024 / 8) + (bid >> 3);
  const int bx = wg & 31, by = wg >> 5;
  const int bm0 = by * 256, bn0 = bx * 128;

  // per-lane swizzled fragment byte offset within a 1KB subtile
  int foff = (lane & 15) * 64 + ((lane >> 4) << 4);
  foff ^= ((foff >> 9) & 1) << 5;

  // prologue: tiles 0,1 into bufs 0,1 (6 loads/wave); retire own tile-0 loads; publish.
  stage_tile<0>(A, B, smem, bm0, bn0, w, lane, 0);
  stage_tile<1>(A, B, smem, bm0, bn0, w, lane, 1);
  vmwait<3>();
  bar();

  f32x4 acc[4][4] = {};

  int kt = 0;
  while (kt + 3 <= KT32) {
    phase<0>(A, B, smem, bm0, bn0, w, lane, wm, wn, foff, kt,     acc);
    phase<1>(A, B, smem, bm0, bn0, w, lane, wm, wn, foff, kt + 1, acc);
    phase<2>(A, B, smem, bm0, bn0, w, lane, wm, wn, foff, kt + 2, acc);
    kt += 3;
  }
  // KT32 = 128 = 42*3 + 2: tail tiles 126 (buf 0), 127 (buf 1)
  phase<0>(A, B, smem, bm0, bn0, w, lane, wm, wn, foff, 126, acc);
  phase<1>(A, B, smem, bm0, bn0, w, lane, wm, wn, foff, 127, acc);

  // epilogue: C/D layout col=lane&15, row=4*(lane>>4)+reg
  const int orow = (lane >> 4) << 2;
#pragma unroll
  for (int mi = 0; mi < 4; ++mi) {
#pragma unroll
    for (int ni = 0; ni < 4; ++ni) {
      float* cp = C + (size_t)(bm0 + wm * 64 + mi * 16 + orow) * GN
                    + (bn0 + wn * 64 + ni * 16 + (lane & 15));
#pragma unroll
      for (int r = 0; r < 4; ++r)
        cp[(size_t)r * GN] = acc[mi][ni][r];
    }
  }
}

extern "C" void kernel_launch(void* const* d_in, const int* in_sizes, int n_in,
                              void* d_out, int out_size, void* d_ws, size_t ws_size,
                              hipStream_t stream) {
  const float* x  = (const float*)d_in[0];   // [4,2048,4096] f32
  const float* w  = (const float*)d_in[1];   // [4096,4096]   f32
  const float* lA = (const float*)d_in[2];   // [16,4096]     f32
  const float* lB = (const float*)d_in[3];   // [4096,16]     f32
  float* out = (float*)d_out;                // [4,2048,4096] f32

  const int M = GM, N = GN, K = GK;

  unsigned short* xb = (unsigned short*)d_ws;          // M*K bf16 = 64MB
  unsigned short* wb = xb + (size_t)M * K;             // N*K bf16 = 32MB

  cvt_x_kernel<<<dim3((M * K / 8) / 256), dim3(256), 0, stream>>>(x, xb);
  weff_kernel<<<dim3((N / 8) * (K / 8) / 256), dim3(256), 0, stream>>>(w, lA, lB, wb);
  gemm_bt_kernel<<<dim3((M / 256) * (N / 128)), dim3(512), 0, stream>>>(xb, wb, out);
}

// Round 13
// 288.518 us; speedup vs baseline: 1.1796x; 1.1796x over previous
//
#include <hip/hip_runtime.h>
#include <stdint.h>

typedef __attribute__((ext_vector_type(8))) short bf16x8;
typedef __attribute__((ext_vector_type(4))) float f32x4;

#define GM 8192
#define GN 4096
#define GK 4096
#define KTILES (GK / 64)

__device__ __forceinline__ unsigned short f2bf(float f) {
  union { float f; unsigned int u; } c; c.f = f;
  unsigned int u = c.u;
  unsigned int r = u + 0x7FFFu + ((u >> 16) & 1u);   // round-to-nearest-even
  return (unsigned short)(r >> 16);
}

// ---------------- x (f32) -> bf16, 8 elems/thread ----------------
__global__ __launch_bounds__(256) void cvt_x_kernel(const float* __restrict__ x,
                                                    unsigned short* __restrict__ xb) {
  int i = blockIdx.x * 256 + threadIdx.x;
  const float4* p = (const float4*)x + (size_t)i * 2;
  float4 a = p[0], b = p[1];
  unsigned short t[8] = { f2bf(a.x), f2bf(a.y), f2bf(a.z), f2bf(a.w),
                          f2bf(b.x), f2bf(b.y), f2bf(b.z), f2bf(b.w) };
  int4 pk; __builtin_memcpy(&pk, t, 16);
  ((int4*)xb)[i] = pk;
}

// -------- W_eff = weight + 2 * lora_B @ lora_A -> bf16 --------
__global__ __launch_bounds__(256) void weff_kernel(const float* __restrict__ w,
                                                   const float* __restrict__ lA,
                                                   const float* __restrict__ lB,
                                                   unsigned short* __restrict__ wb) {
  const int K = GK;
  int idx = blockIdx.x * 256 + threadIdx.x;   // over (N/8)*(K/8) = 512*512
  int cg = idx & 511;
  int rg = idx >> 9;
  int i0 = cg << 3;
  int o0 = rg << 3;

  float acc[8][8];
#pragma unroll
  for (int r = 0; r < 8; ++r)
#pragma unroll
    for (int c = 0; c < 8; ++c) acc[r][c] = 0.f;

#pragma unroll
  for (int r = 0; r < 16; ++r) {
    float4 a0 = *(const float4*)(lA + (size_t)r * K + i0);
    float4 a1 = *(const float4*)(lA + (size_t)r * K + i0 + 4);
    float av[8] = { a0.x, a0.y, a0.z, a0.w, a1.x, a1.y, a1.z, a1.w };
#pragma unroll
    for (int row = 0; row < 8; ++row) {
      float b = lB[(size_t)(o0 + row) * 16 + r];
#pragma unroll
      for (int c = 0; c < 8; ++c) acc[row][c] += b * av[c];
    }
  }

#pragma unroll
  for (int row = 0; row < 8; ++row) {
    float4 w0 = *(const float4*)(w + (size_t)(o0 + row) * K + i0);
    float4 w1 = *(const float4*)(w + (size_t)(o0 + row) * K + i0 + 4);
    unsigned short t[8] = {
      f2bf(w0.x + 2.0f * acc[row][0]), f2bf(w0.y + 2.0f * acc[row][1]),
      f2bf(w0.z + 2.0f * acc[row][2]), f2bf(w0.w + 2.0f * acc[row][3]),
      f2bf(w1.x + 2.0f * acc[row][4]), f2bf(w1.y + 2.0f * acc[row][5]),
      f2bf(w1.z + 2.0f * acc[row][6]), f2bf(w1.w + 2.0f * acc[row][7]) };
    int4 pk; __builtin_memcpy(&pk, t, 16);
    *(int4*)(wb + (size_t)(o0 + row) * K + i0) = pk;
  }
}

// ====== 256x256 8-phase bf16 GEMM, double buffer (2x64KB), 1 vmcnt/K-tile: C = A * B^T ======
// 8 waves (2M x 4N), 128x64 C per wave, BK=64. st_16x32 swizzle (0 conflicts).
// Stage-ahead = 7 half-tiles (per-wave: 2 loads/half): P0(kt)->h3(kt+1), P1->h0(kt+2),
// P2->h1(kt+2), P3->h2(kt+2) + vmcnt(6) [retires ALL of tile kt+1; keeps 3 halves in flight].
// Phase = {ds_read subtile + stage 1 half [+lgkm(8) if 12 reads]} -> bar -> lgkm(0) ->
// setprio(1) 16 MFMA setprio(0) -> bar.  The post-bar lgkm(0) is load-bearing for WAR:
// every stage-write to a region is issued >= 1 barrier after that region's reads drained.

__device__ __forceinline__ void gload16(const unsigned short* g, char* l) {
  __builtin_amdgcn_global_load_lds((__attribute__((address_space(1))) void*)g,
                                   (__attribute__((address_space(3))) void*)l, 16, 0, 0);
}

__device__ __forceinline__ void bar() {
  asm volatile("" ::: "memory");
  __builtin_amdgcn_s_barrier();
  asm volatile("" ::: "memory");
}

template <int N>
__device__ __forceinline__ void vmwait() {
  if constexpr (N == 0)      asm volatile("s_waitcnt vmcnt(0)" ::: "memory");
  else if constexpr (N == 6) asm volatile("s_waitcnt vmcnt(6)" ::: "memory");
}

__device__ __forceinline__ void lgkm0() {
  asm volatile("s_waitcnt lgkmcnt(0)" ::: "memory");
}
__device__ __forceinline__ void lgkm8() {
  asm volatile("s_waitcnt lgkmcnt(8)" ::: "memory");
}

#define MFMA_BF16(a, b, c) __builtin_amdgcn_mfma_f32_16x16x32_bf16((a), (b), (c), 0, 0, 0)

// HALF 0: A subtiles {0..3, 8..11}   (avLo, read at P0)
// HALF 1: B subtiles {0,1,4,5,8,9,12,13}   (bv0, read at P0)
// HALF 2: B subtiles {2,3,6,7,10,11,14,15} (bv1, read at P1)
// HALF 3: A subtiles {4..7, 12..15}  (avHi, read at P2)
template <int HALF, int BUF>
__device__ __forceinline__ void stage_half(const unsigned short* A, const unsigned short* B,
                                           char* smem, int bm0, int bn0, int w, int lane,
                                           int kt) {
  int sr, isB;
  if constexpr (HALF == 0)      { sr = w + (w & 4);                   isB = 0; }
  else if constexpr (HALF == 1) { sr = ((w >> 1) << 2) + (w & 1);     isB = 1; }
  else if constexpr (HALF == 2) { sr = ((w >> 1) << 2) + (w & 1) + 2; isB = 1; }
  else                          { sr = w + (w & 4) + 4;               isB = 0; }
  const unsigned short* mat = isB ? B : A;
  const int grow = (isB ? bn0 : bm0) + sr * 16 + (lane >> 2);
  const int gcol = ((lane & 3) * 8) ^ ((lane & 32) ? 16 : 0);   // pre-swizzled source col
#pragma unroll
  for (int sc = 0; sc < 2; ++sc) {
    const unsigned short* src = mat + (size_t)grow * GK + kt * 64 + sc * 32 + gcol;
    char* dst = smem + BUF * 65536 + (isB ? 32768 : 0) + ((sr * 2 + sc) << 10);
    gload16(src, dst);
  }
}

__device__ __forceinline__ bf16x8 ldsA(const char* smem, int buf, int sr, int sc, int foff) {
  return *(const bf16x8*)(smem + buf * 65536 + ((sr * 2 + sc) << 10) + foff);
}
__device__ __forceinline__ bf16x8 ldsB(const char* smem, int buf, int sr, int sc, int foff) {
  return *(const bf16x8*)(smem + buf * 65536 + 32768 + ((sr * 2 + sc) << 10) + foff);
}

// TAIL: 0 = steady, 1 = kt == KTILES-2 (P0 stages h3(63) only; P3 vmcnt(0)), 2 = last tile
template <int CUR, int TAIL>
__device__ __forceinline__ void ktile(const unsigned short* __restrict__ A,
                                      const unsigned short* __restrict__ B,
                                      char* smem, int bm0, int bn0, int w, int lane,
                                      int wm, int wn, int foff, int kt,
                                      bf16x8 (&av)[4][2], bf16x8 (&bv0)[2][2],
                                      bf16x8 (&bv1)[2][2], f32x4 (&acc)[8][4]) {
  constexpr int NXT = CUR ^ 1;

  // ---- P0: stage h3(kt+1); read avLo(kt)+bv0(kt) [tile kt published @P3(kt-1)] ----
  if constexpr (TAIL < 2) stage_half<3, NXT>(A, B, smem, bm0, bn0, w, lane, kt + 1);
#pragma unroll
  for (int mi = 0; mi < 4; ++mi) {
    av[mi][0] = ldsA(smem, CUR, wm * 8 + mi, 0, foff);
    av[mi][1] = ldsA(smem, CUR, wm * 8 + mi, 1, foff);
  }
#pragma unroll
  for (int ni = 0; ni < 2; ++ni) {
    bv0[ni][0] = ldsB(smem, CUR, wn * 4 + ni, 0, foff);
    bv0[ni][1] = ldsB(smem, CUR, wn * 4 + ni, 1, foff);
  }
  lgkm8();          // 12 reads issued this phase (template: optional partial drain)
  bar();
  lgkm0();
  __builtin_amdgcn_s_setprio(1);
#pragma unroll
  for (int mi = 0; mi < 4; ++mi) {
    acc[mi][0] = MFMA_BF16(av[mi][0], bv0[0][0], acc[mi][0]);
    acc[mi][0] = MFMA_BF16(av[mi][1], bv0[0][1], acc[mi][0]);
    acc[mi][1] = MFMA_BF16(av[mi][0], bv0[1][0], acc[mi][1]);
    acc[mi][1] = MFMA_BF16(av[mi][1], bv0[1][1], acc[mi][1]);
  }
  __builtin_amdgcn_s_setprio(0);
  bar();

  // ---- P1: stage h0(kt+2); read bv1(kt) ----
  if constexpr (TAIL == 0) stage_half<0, CUR>(A, B, smem, bm0, bn0, w, lane, kt + 2);
#pragma unroll
  for (int ni = 0; ni < 2; ++ni) {
    bv1[ni][0] = ldsB(smem, CUR, wn * 4 + 2 + ni, 0, foff);
    bv1[ni][1] = ldsB(smem, CUR, wn * 4 + 2 + ni, 1, foff);
  }
  bar();
  lgkm0();
  __builtin_amdgcn_s_setprio(1);
#pragma unroll
  for (int mi = 0; mi < 4; ++mi) {
    acc[mi][2] = MFMA_BF16(av[mi][0], bv1[0][0], acc[mi][2]);
    acc[mi][2] = MFMA_BF16(av[mi][1], bv1[0][1], acc[mi][2]);
    acc[mi][3] = MFMA_BF16(av[mi][0], bv1[1][0], acc[mi][3]);
    acc[mi][3] = MFMA_BF16(av[mi][1], bv1[1][1], acc[mi][3]);
  }
  __builtin_amdgcn_s_setprio(0);
  bar();

  // ---- P2: stage h1(kt+2); read avHi(kt) ----
  if constexpr (TAIL == 0) stage_half<1, CUR>(A, B, smem, bm0, bn0, w, lane, kt + 2);
#pragma unroll
  for (int mi = 0; mi < 4; ++mi) {
    av[mi][0] = ldsA(smem, CUR, wm * 8 + 4 + mi, 0, foff);
    av[mi][1] = ldsA(smem, CUR, wm * 8 + 4 + mi, 1, foff);
  }
  bar();
  lgkm0();
  __builtin_amdgcn_s_setprio(1);
#pragma unroll
  for (int mi = 0; mi < 4; ++mi) {
    acc[4 + mi][2] = MFMA_BF16(av[mi][0], bv1[0][0], acc[4 + mi][2]);
    acc[4 + mi][2] = MFMA_BF16(av[mi][1], bv1[0][1], acc[4 + mi][2]);
    acc[4 + mi][3] = MFMA_BF16(av[mi][0], bv1[1][0], acc[4 + mi][3]);
    acc[4 + mi][3] = MFMA_BF16(av[mi][1], bv1[1][1], acc[4 + mi][3]);
  }
  __builtin_amdgcn_s_setprio(0);
  bar();

  // ---- P3: stage h2(kt+2); ONE per-tile vmcnt: retires tile kt+1 in full ----
  if constexpr (TAIL == 0) {
    stage_half<2, CUR>(A, B, smem, bm0, bn0, w, lane, kt + 2);
    vmwait<6>();     // keep newest 3 halves (h0,h1,h2 of kt+2); h3(kt+1) and older retired
  } else if constexpr (TAIL == 1) {
    vmwait<0>();     // publish final tile
  }
  bar();
  __builtin_amdgcn_s_setprio(1);
#pragma unroll
  for (int mi = 0; mi < 4; ++mi) {
    acc[4 + mi][0] = MFMA_BF16(av[mi][0], bv0[0][0], acc[4 + mi][0]);
    acc[4 + mi][0] = MFMA_BF16(av[mi][1], bv0[0][1], acc[4 + mi][0]);
    acc[4 + mi][1] = MFMA_BF16(av[mi][0], bv0[1][0], acc[4 + mi][1]);
    acc[4 + mi][1] = MFMA_BF16(av[mi][1], bv0[1][1], acc[4 + mi][1]);
  }
  __builtin_amdgcn_s_setprio(0);
  bar();
}

__global__ __launch_bounds__(512, 2) void gemm_bt_kernel(const unsigned short* __restrict__ A,
                                                         const unsigned short* __restrict__ B,
                                                         float* __restrict__ C) {
  __shared__ alignas(16) char smem[131072];   // 2 x 64 KB

  const int t = threadIdx.x, lane = t & 63, w = t >> 6;
  const int wm = w >> 2, wn = w & 3;     // 2 x 4 wave grid

  // bijective XCD-chunked swizzle: 512 blocks, 512 % 8 == 0
  const int bid = blockIdx.x;
  const int wg  = (bid & 7) * (512 / 8) + (bid >> 3);
  const int bx = wg & 15, by = wg >> 4;
  const int bm0 = by * 256, bn0 = bx * 256;

  // per-lane swizzled fragment byte offset within a 1KB subtile
  int foff = (lane & 15) * 64 + ((lane >> 4) << 4);
  foff ^= ((foff >> 9) & 1) << 5;

  // prologue: 7 half-tiles ahead (tile 0 full + h0,h1,h2 of tile 1) = 14 loads/wave;
  // vmcnt(6) retires tile 0's 8, keeps 3 halves in flight; barrier publishes tile 0.
  stage_half<0, 0>(A, B, smem, bm0, bn0, w, lane, 0);
  stage_half<1, 0>(A, B, smem, bm0, bn0, w, lane, 0);
  stage_half<2, 0>(A, B, smem, bm0, bn0, w, lane, 0);
  stage_half<3, 0>(A, B, smem, bm0, bn0, w, lane, 0);
  stage_half<0, 1>(A, B, smem, bm0, bn0, w, lane, 1);
  stage_half<1, 1>(A, B, smem, bm0, bn0, w, lane, 1);
  stage_half<2, 1>(A, B, smem, bm0, bn0, w, lane, 1);
  vmwait<6>();
  bar();

  f32x4 acc[8][4] = {};
  bf16x8 av[4][2], bv0[2][2], bv1[2][2];

  // KTILES = 64: steady tiles 0..61, tail tiles 62 (TAIL1), 63 (TAIL2)
  for (int kt = 0; kt + 2 <= KTILES - 2; kt += 2) {
    ktile<0, 0>(A, B, smem, bm0, bn0, w, lane, wm, wn, foff, kt,     av, bv0, bv1, acc);
    ktile<1, 0>(A, B, smem, bm0, bn0, w, lane, wm, wn, foff, kt + 1, av, bv0, bv1, acc);
  }
  ktile<0, 1>(A, B, smem, bm0, bn0, w, lane, wm, wn, foff, KTILES - 2, av, bv0, bv1, acc);
  ktile<1, 2>(A, B, smem, bm0, bn0, w, lane, wm, wn, foff, KTILES - 1, av, bv0, bv1, acc);

  // epilogue: C/D layout col=lane&15, row=4*(lane>>4)+reg
  const int orow = (lane >> 4) << 2;
#pragma unroll
  for (int mi = 0; mi < 8; ++mi) {
#pragma unroll
    for (int ni = 0; ni < 4; ++ni) {
      float* cp = C + (size_t)(bm0 + wm * 128 + mi * 16 + orow) * GN
                    + (bn0 + wn * 64 + ni * 16 + (lane & 15));
#pragma unroll
      for (int r = 0; r < 4; ++r)
        cp[(size_t)r * GN] = acc[mi][ni][r];
    }
  }
}

extern "C" void kernel_launch(void* const* d_in, const int* in_sizes, int n_in,
                              void* d_out, int out_size, void* d_ws, size_t ws_size,
                              hipStream_t stream) {
  const float* x  = (const float*)d_in[0];   // [4,2048,4096] f32
  const float* w  = (const float*)d_in[1];   // [4096,4096]   f32
  const float* lA = (const float*)d_in[2];   // [16,4096]     f32
  const float* lB = (const float*)d_in[3];   // [4096,16]     f32
  float* out = (float*)d_out;                // [4,2048,4096] f32

  const int M = GM, N = GN, K = GK;

  unsigned short* xb = (unsigned short*)d_ws;          // M*K bf16 = 64MB
  unsigned short* wb = xb + (size_t)M * K;             // N*K bf16 = 32MB

  cvt_x_kernel<<<dim3((M * K / 8) / 256), dim3(256), 0, stream>>>(x, xb);
  weff_kernel<<<dim3((N / 8) * (K / 8) / 256), dim3(256), 0, stream>>>(w, lA, lB, wb);
  gemm_bt_kernel<<<dim3((M / 256) * (N / 256)), dim3(512), 0, stream>>>(xb, wb, out);
}